// Round 18
// baseline (1831.649 us; speedup 1.0000x reference)
//
// R18 = R17 with GEMM1 retiled 128x64 -> 64x64 (48KB LDS, 3 blocks/CU, grid 1024)
#include <hip/hip_runtime.h>
#include <hip/hip_bf16.h>
#include <cstdint>

#define BATCH 4096
#define DIM   512
#define HID   1024
#define TSTEPS 20

typedef unsigned short u16;
typedef short s16x8 __attribute__((ext_vector_type(8)));
typedef float f32x4 __attribute__((ext_vector_type(4)));

__device__ __forceinline__ u16 f2bf(float f) {
    unsigned int u = __float_as_uint(f);
    u = (u + 0x7FFFu + ((u >> 16) & 1u)) >> 16;   // RNE
    return (u16)u;
}

__device__ __forceinline__ float fast_tanh(float x) {
    float ax = __builtin_fabsf(x);
    float e  = __expf(2.0f * ax);                 // inf for large ax -> t = 1
    float t  = 1.0f - 2.0f * __builtin_amdgcn_rcpf(e + 1.0f);
    return __builtin_copysignf(t, x);
}

// out[0] = x0 ; ybf = bf16(x0)
__global__ void init_state(const float* __restrict__ x0, float* __restrict__ out0,
                           u16* __restrict__ ybf, int n) {
    int i = blockIdx.x * blockDim.x + threadIdx.x;
    if (i < n) { float v = x0[i]; out0[i] = v; ybf[i] = f2bf(v); }
}

// Wt[n*K + k] = bf16(W[k*N + n])   (W is [K][N] row-major)
__global__ void transpose_convert(const float* __restrict__ W, u16* __restrict__ Wt,
                                  int K, int N) {
    int n = blockIdx.x * 32 + threadIdx.x;
    int k = blockIdx.y * 8  + threadIdx.y;
    if (n < N && k < K) Wt[(size_t)n * K + k] = f2bf(W[(size_t)k * N + n]);
}

// C = A[M,K] * Bt[N,K]^T, fused epilogue. (DEPTH+1)-buffer depth-DEPTH pipelined
// K-loop, counted vmcnt, ONE barrier per iteration (WAR covered by next top barrier).
// EPI==0 : act = bf16(fast_tanh(C + bias))      (GEMM1)
// EPI==1..4 : RK4 stage epilogues               (GEMM2, N == DIM)
template<int BM, int BN, int EPI, int DEPTH>
__global__ __launch_bounds__(256, 2) void gemm_bt(
    const u16* __restrict__ A,
    const u16* __restrict__ Bt,
    const float* __restrict__ bias,
    int M, int N, int K,
    u16* __restrict__ actOut,
    const float* __restrict__ ybase,
    float* __restrict__ ynext,
    float* __restrict__ accum,
    u16* __restrict__ ybf,
    const float* __restrict__ tgrid, int step)
{
    constexpr int AC = BM / 8;          // A chunks (1 KiB each) per K-tile
    constexpr int BC = BN / 8;
    constexpr int CPW = (AC + BC) / 4;  // global_load_lds per thread per tile
    constexpr int NBUF = DEPTH + 1;
    static_assert((DEPTH == 2 && (CPW == 6 || CPW == 4)) || (DEPTH == 3 && CPW == 4),
                  "vmcnt literals below assume these configs");
    constexpr int WM = BM / 32;
    constexpr int WN = BN / 32;
    constexpr int BUFE = (BM + BN) * 64;   // u16 elems per LDS buffer

    __shared__ u16 lds[NBUF * BUFE];

    const int tid  = threadIdx.x;
    const int lane = tid & 63;
    const int wid  = tid >> 6;
    const int wy   = wid >> 1;
    const int wx   = wid & 1;
    const int brow = blockIdx.x * BM;
    const int bcol = blockIdx.y * BN;

    const int srow = lane >> 3;                    // row within 8-row group
    const int scol = ((lane & 7) ^ srow) * 8;      // pre-swizzled k offset (elems)

    f32x4 acc[WM][WN];
#pragma unroll
    for (int m = 0; m < WM; ++m)
#pragma unroll
        for (int n = 0; n < WN; ++n)
            acc[m][n] = (f32x4){0.f, 0.f, 0.f, 0.f};

    auto stage = [&](int buf, int kt) {
        const int k0 = kt * 64;
        u16* base = &lds[buf * BUFE];
#pragma unroll
        for (int c0 = 0; c0 < CPW; ++c0) {
            int c = wid * CPW + c0;            // wave-uniform
            if (c < AC) {
                int row = c * 8 + srow;
                const u16* g = A + (size_t)(brow + row) * K + k0 + scol;
                __builtin_amdgcn_global_load_lds(
                    (const __attribute__((address_space(1))) unsigned int*)g,
                    (__attribute__((address_space(3))) unsigned int*)&base[c * 512],
                    16, 0, 0);
            } else {
                int cb = c - AC;
                int row = cb * 8 + srow;
                const u16* g = Bt + (size_t)(bcol + row) * K + k0 + scol;
                __builtin_amdgcn_global_load_lds(
                    (const __attribute__((address_space(1))) unsigned int*)g,
                    (__attribute__((address_space(3))) unsigned int*)&base[BM * 64 + cb * 512],
                    16, 0, 0);
            }
        }
    };

    const int NT = K / 64;

    // prologue: DEPTH tiles in flight
#pragma unroll
    for (int d = 0; d < DEPTH; ++d) stage(d, d);

    for (int kt = 0; kt < NT; ++kt) {
        // wait until tile kt's loads complete; keep later tiles in flight
        if constexpr (DEPTH == 2 && CPW == 6) {
            if (kt < NT - 1) asm volatile("s_waitcnt vmcnt(6)" ::: "memory");
            else             asm volatile("s_waitcnt vmcnt(0)" ::: "memory");
        } else if constexpr (DEPTH == 2 && CPW == 4) {
            if (kt < NT - 1) asm volatile("s_waitcnt vmcnt(4)" ::: "memory");
            else             asm volatile("s_waitcnt vmcnt(0)" ::: "memory");
        } else {
            if (kt < NT - 2)       asm volatile("s_waitcnt vmcnt(8)" ::: "memory");
            else if (kt == NT - 2) asm volatile("s_waitcnt vmcnt(4)" ::: "memory");
            else                   asm volatile("s_waitcnt vmcnt(0)" ::: "memory");
        }
        // single barrier: all waves' tile-kt loads landed; also seals WAR for the
        // buffer staged below (last read by all waves in iter kt-1).
        __builtin_amdgcn_s_barrier();

        const char* lb = (const char*)&lds[(kt % NBUF) * BUFE];

        s16x8 af[2][WM], bfr[2][WN];
#pragma unroll
        for (int ks = 0; ks < 2; ++ks) {
#pragma unroll
            for (int m = 0; m < WM; ++m) {
                int row = wy * (BM / 2) + m * 16 + (lane & 15);
                unsigned byte = (unsigned)(row * 128 + (ks * 32 + (lane >> 4) * 8) * 2);
                byte ^= (unsigned)((row & 7) << 4);
                af[ks][m] = *(const s16x8*)(lb + byte);
            }
#pragma unroll
            for (int n = 0; n < WN; ++n) {
                int row = wx * (BN / 2) + n * 16 + (lane & 15);
                unsigned byte = (unsigned)(BM * 128 + row * 128 + (ks * 32 + (lane >> 4) * 8) * 2);
                byte ^= (unsigned)((row & 7) << 4);
                bfr[ks][n] = *(const s16x8*)(lb + byte);
            }
        }

        // issue tile kt+DEPTH while tile kt computes
        if (kt + DEPTH < NT) stage((kt + DEPTH) % NBUF, kt + DEPTH);

#pragma unroll
        for (int ks = 0; ks < 2; ++ks)
#pragma unroll
            for (int m = 0; m < WM; ++m)
#pragma unroll
                for (int n = 0; n < WN; ++n)
                    acc[m][n] = __builtin_amdgcn_mfma_f32_16x16x32_bf16(
                        af[ks][m], bfr[ks][n], acc[m][n], 0, 0, 0);
    }

    // ---- epilogue ----
    float dtv = 0.f;
    if constexpr (EPI >= 1) dtv = tgrid[step + 1] - tgrid[step];

#pragma unroll
    for (int m = 0; m < WM; ++m) {
        int row0 = brow + wy * (BM / 2) + m * 16 + (lane >> 4) * 4;
#pragma unroll
        for (int n = 0; n < WN; ++n) {
            int col = bcol + wx * (BN / 2) + n * 16 + (lane & 15);
            float bv = bias[col];
#pragma unroll
            for (int j = 0; j < 4; ++j) {
                int row = row0 + j;
                float v = acc[m][n][j] + bv;
                if constexpr (EPI == 0) {
                    actOut[(size_t)row * HID + col] = f2bf(fast_tanh(v));
                } else {
                    size_t idx = (size_t)row * DIM + col;
                    float yb = ybase[idx];
                    if constexpr (EPI == 1) {
                        accum[idx] = v;
                        ybf[idx] = f2bf(yb + 0.5f * dtv * v);
                    } else if constexpr (EPI == 2) {
                        accum[idx] += 2.0f * v;
                        ybf[idx] = f2bf(yb + 0.5f * dtv * v);
                    } else if constexpr (EPI == 3) {
                        accum[idx] += 2.0f * v;
                        ybf[idx] = f2bf(yb + dtv * v);
                    } else {  // EPI == 4
                        float yn = yb + (dtv * (1.0f / 6.0f)) * (accum[idx] + v);
                        ynext[idx] = yn;
                        ybf[idx] = f2bf(yn);
                    }
                }
            }
        }
    }
}

extern "C" void kernel_launch(void* const* d_in, const int* in_sizes, int n_in,
                              void* d_out, int out_size, void* d_ws, size_t ws_size,
                              hipStream_t stream) {
    (void)in_sizes; (void)n_in; (void)out_size; (void)ws_size;
    const float* x0 = (const float*)d_in[0];
    const float* t  = (const float*)d_in[1];
    const float* W1 = (const float*)d_in[2];
    const float* b1 = (const float*)d_in[3];
    const float* W2 = (const float*)d_in[4];
    const float* b2 = (const float*)d_in[5];
    float* out = (float*)d_out;

    char* ws = (char*)d_ws;
    u16*   ybf   = (u16*)  (ws);               //  4 MB  [4096,512]  bf16
    u16*   act   = (u16*)  (ws + (4u  << 20)); //  8 MB  [4096,1024] bf16
    float* accum = (float*)(ws + (12u << 20)); //  8 MB  [4096,512]  f32
    u16*   W1T   = (u16*)  (ws + (20u << 20)); //  1 MB  [1024,512]  bf16
    u16*   W2T   = (u16*)  (ws + (21u << 20)); //  1 MB  [512,1024]  bf16

    init_state<<<(BATCH * DIM + 255) / 256, 256, 0, stream>>>(x0, out, ybf, BATCH * DIM);
    transpose_convert<<<dim3(HID / 32, DIM / 8), dim3(32, 8), 0, stream>>>(W1, W1T, DIM, HID);
    transpose_convert<<<dim3(DIM / 32, HID / 8), dim3(32, 8), 0, stream>>>(W2, W2T, HID, DIM);

    dim3 blk(256);
    dim3 g1(BATCH / 64, HID / 64);     // 64 x 16 = 1024 blocks (3 resident/CU, 48KB LDS)
    dim3 g2(BATCH / 64, DIM / 64);     // 64 x 8  = 512 blocks (2 per CU)

    for (int s = 0; s < TSTEPS - 1; ++s) {
        const float* yb_s = out + (size_t)s * BATCH * DIM;
        float*       yn_s = out + (size_t)(s + 1) * BATCH * DIM;

        // stage 1: k1 = f(y)
        gemm_bt<64,64,0,2><<<g1, blk, 0, stream>>>(ybf, W1T, b1, BATCH, HID, DIM,
                                                   act, nullptr, nullptr, nullptr, nullptr, nullptr, 0);
        gemm_bt<64,64,1,3><<<g2, blk, 0, stream>>>(act, W2T, b2, BATCH, DIM, HID,
                                                   nullptr, yb_s, yn_s, accum, ybf, t, s);
        // stage 2: k2 = f(y + dt/2 * k1)
        gemm_bt<64,64,0,2><<<g1, blk, 0, stream>>>(ybf, W1T, b1, BATCH, HID, DIM,
                                                   act, nullptr, nullptr, nullptr, nullptr, nullptr, 0);
        gemm_bt<64,64,2,3><<<g2, blk, 0, stream>>>(act, W2T, b2, BATCH, DIM, HID,
                                                   nullptr, yb_s, yn_s, accum, ybf, t, s);
        // stage 3: k3 = f(y + dt/2 * k2)
        gemm_bt<64,64,0,2><<<g1, blk, 0, stream>>>(ybf, W1T, b1, BATCH, HID, DIM,
                                                   act, nullptr, nullptr, nullptr, nullptr, nullptr, 0);
        gemm_bt<64,64,3,3><<<g2, blk, 0, stream>>>(act, W2T, b2, BATCH, DIM, HID,
                                                   nullptr, yb_s, yn_s, accum, ybf, t, s);
        // stage 4: y' = y + dt/6 * (k1 + 2k2 + 2k3 + k4)
        gemm_bt<64,64,0,2><<<g1, blk, 0, stream>>>(ybf, W1T, b1, BATCH, HID, DIM,
                                                   act, nullptr, nullptr, nullptr, nullptr, nullptr, 0);
        gemm_bt<64,64,4,3><<<g2, blk, 0, stream>>>(act, W2T, b2, BATCH, DIM, HID,
                                                   nullptr, yb_s, yn_s, accum, ybf, t, s);
    }
}

// Round 19
// 1777.800 us; speedup vs baseline: 1.0303x; 1.0303x over previous
//
// R19 = R17 (GEMM1 128x64 restored) + GEMM2 epilogue prefetch (yb/accum -> regs before K-loop)
#include <hip/hip_runtime.h>
#include <hip/hip_bf16.h>
#include <cstdint>

#define BATCH 4096
#define DIM   512
#define HID   1024
#define TSTEPS 20

typedef unsigned short u16;
typedef short s16x8 __attribute__((ext_vector_type(8)));
typedef float f32x4 __attribute__((ext_vector_type(4)));

__device__ __forceinline__ u16 f2bf(float f) {
    unsigned int u = __float_as_uint(f);
    u = (u + 0x7FFFu + ((u >> 16) & 1u)) >> 16;   // RNE
    return (u16)u;
}

__device__ __forceinline__ float fast_tanh(float x) {
    float ax = __builtin_fabsf(x);
    float e  = __expf(2.0f * ax);                 // inf for large ax -> t = 1
    float t  = 1.0f - 2.0f * __builtin_amdgcn_rcpf(e + 1.0f);
    return __builtin_copysignf(t, x);
}

// out[0] = x0 ; ybf = bf16(x0)
__global__ void init_state(const float* __restrict__ x0, float* __restrict__ out0,
                           u16* __restrict__ ybf, int n) {
    int i = blockIdx.x * blockDim.x + threadIdx.x;
    if (i < n) { float v = x0[i]; out0[i] = v; ybf[i] = f2bf(v); }
}

// Wt[n*K + k] = bf16(W[k*N + n])   (W is [K][N] row-major)
__global__ void transpose_convert(const float* __restrict__ W, u16* __restrict__ Wt,
                                  int K, int N) {
    int n = blockIdx.x * 32 + threadIdx.x;
    int k = blockIdx.y * 8  + threadIdx.y;
    if (n < N && k < K) Wt[(size_t)n * K + k] = f2bf(W[(size_t)k * N + n]);
}

// C = A[M,K] * Bt[N,K]^T, fused epilogue. (DEPTH+1)-buffer depth-DEPTH pipelined
// K-loop, counted vmcnt, ONE barrier per iteration. EPI>=1 prefetches its
// epilogue operands (ybase/accum) into registers BEFORE staging: they are the
// oldest VMEM ops, so every counted vmcnt wait retires them first (safe).
// EPI==0 : act = bf16(fast_tanh(C + bias))      (GEMM1)
// EPI==1..4 : RK4 stage epilogues               (GEMM2, N == DIM)
template<int BM, int BN, int EPI, int DEPTH>
__global__ __launch_bounds__(256, 2) void gemm_bt(
    const u16* __restrict__ A,
    const u16* __restrict__ Bt,
    const float* __restrict__ bias,
    int M, int N, int K,
    u16* __restrict__ actOut,
    const float* __restrict__ ybase,
    float* __restrict__ ynext,
    float* __restrict__ accum,
    u16* __restrict__ ybf,
    const float* __restrict__ tgrid, int step)
{
    constexpr int AC = BM / 8;          // A chunks (1 KiB each) per K-tile
    constexpr int BC = BN / 8;
    constexpr int CPW = (AC + BC) / 4;  // global_load_lds per thread per tile
    constexpr int NBUF = DEPTH + 1;
    static_assert((DEPTH == 2 && CPW == 6) || (DEPTH == 3 && CPW == 4),
                  "vmcnt literals below assume these configs");
    constexpr int WM = BM / 32;
    constexpr int WN = BN / 32;
    constexpr int BUFE = (BM + BN) * 64;   // u16 elems per LDS buffer

    __shared__ u16 lds[NBUF * BUFE];

    const int tid  = threadIdx.x;
    const int lane = tid & 63;
    const int wid  = tid >> 6;
    const int wy   = wid >> 1;
    const int wx   = wid & 1;
    const int brow = blockIdx.x * BM;
    const int bcol = blockIdx.y * BN;

    const int srow = lane >> 3;                    // row within 8-row group
    const int scol = ((lane & 7) ^ srow) * 8;      // pre-swizzled k offset (elems)

    f32x4 acc[WM][WN];
#pragma unroll
    for (int m = 0; m < WM; ++m)
#pragma unroll
        for (int n = 0; n < WN; ++n)
            acc[m][n] = (f32x4){0.f, 0.f, 0.f, 0.f};

    // ---- EPI>=1: prefetch epilogue operands into registers (oldest VMEM ops) ----
    float pyb[WM][WN][4];
    float pac[WM][WN][4];
    if constexpr (EPI >= 1) {
#pragma unroll
        for (int m = 0; m < WM; ++m) {
            int row0 = brow + wy * (BM / 2) + m * 16 + (lane >> 4) * 4;
#pragma unroll
            for (int n = 0; n < WN; ++n) {
                int col = bcol + wx * (BN / 2) + n * 16 + (lane & 15);
#pragma unroll
                for (int j = 0; j < 4; ++j) {
                    size_t idx = (size_t)(row0 + j) * DIM + col;
                    pyb[m][n][j] = ybase[idx];
                    if constexpr (EPI >= 2) pac[m][n][j] = accum[idx];
                }
            }
        }
        __builtin_amdgcn_sched_barrier(0);   // pin: prefetch issues before staging
    }

    auto stage = [&](int buf, int kt) {
        const int k0 = kt * 64;
        u16* base = &lds[buf * BUFE];
#pragma unroll
        for (int c0 = 0; c0 < CPW; ++c0) {
            int c = wid * CPW + c0;            // wave-uniform
            if (c < AC) {
                int row = c * 8 + srow;
                const u16* g = A + (size_t)(brow + row) * K + k0 + scol;
                __builtin_amdgcn_global_load_lds(
                    (const __attribute__((address_space(1))) unsigned int*)g,
                    (__attribute__((address_space(3))) unsigned int*)&base[c * 512],
                    16, 0, 0);
            } else {
                int cb = c - AC;
                int row = cb * 8 + srow;
                const u16* g = Bt + (size_t)(bcol + row) * K + k0 + scol;
                __builtin_amdgcn_global_load_lds(
                    (const __attribute__((address_space(1))) unsigned int*)g,
                    (__attribute__((address_space(3))) unsigned int*)&base[BM * 64 + cb * 512],
                    16, 0, 0);
            }
        }
    };

    const int NT = K / 64;

    // prologue: DEPTH tiles in flight
#pragma unroll
    for (int d = 0; d < DEPTH; ++d) stage(d, d);

    for (int kt = 0; kt < NT; ++kt) {
        // wait until tile kt's loads complete; keep later tiles in flight
        if constexpr (DEPTH == 2) {
            if (kt < NT - 1) asm volatile("s_waitcnt vmcnt(6)" ::: "memory");
            else             asm volatile("s_waitcnt vmcnt(0)" ::: "memory");
        } else {
            if (kt < NT - 2)       asm volatile("s_waitcnt vmcnt(8)" ::: "memory");
            else if (kt == NT - 2) asm volatile("s_waitcnt vmcnt(4)" ::: "memory");
            else                   asm volatile("s_waitcnt vmcnt(0)" ::: "memory");
        }
        // single barrier: all waves' tile-kt loads landed; also seals WAR for the
        // buffer staged below (last read by all waves in iter kt-1).
        __builtin_amdgcn_s_barrier();

        const char* lb = (const char*)&lds[(kt % NBUF) * BUFE];

        s16x8 af[2][WM], bfr[2][WN];
#pragma unroll
        for (int ks = 0; ks < 2; ++ks) {
#pragma unroll
            for (int m = 0; m < WM; ++m) {
                int row = wy * (BM / 2) + m * 16 + (lane & 15);
                unsigned byte = (unsigned)(row * 128 + (ks * 32 + (lane >> 4) * 8) * 2);
                byte ^= (unsigned)((row & 7) << 4);
                af[ks][m] = *(const s16x8*)(lb + byte);
            }
#pragma unroll
            for (int n = 0; n < WN; ++n) {
                int row = wx * (BN / 2) + n * 16 + (lane & 15);
                unsigned byte = (unsigned)(BM * 128 + row * 128 + (ks * 32 + (lane >> 4) * 8) * 2);
                byte ^= (unsigned)((row & 7) << 4);
                bfr[ks][n] = *(const s16x8*)(lb + byte);
            }
        }

        // issue tile kt+DEPTH while tile kt computes
        if (kt + DEPTH < NT) stage((kt + DEPTH) % NBUF, kt + DEPTH);

#pragma unroll
        for (int ks = 0; ks < 2; ++ks)
#pragma unroll
            for (int m = 0; m < WM; ++m)
#pragma unroll
                for (int n = 0; n < WN; ++n)
                    acc[m][n] = __builtin_amdgcn_mfma_f32_16x16x32_bf16(
                        af[ks][m], bfr[ks][n], acc[m][n], 0, 0, 0);
    }

    // ---- epilogue ----
    float dtv = 0.f;
    if constexpr (EPI >= 1) dtv = tgrid[step + 1] - tgrid[step];

#pragma unroll
    for (int m = 0; m < WM; ++m) {
        int row0 = brow + wy * (BM / 2) + m * 16 + (lane >> 4) * 4;
#pragma unroll
        for (int n = 0; n < WN; ++n) {
            int col = bcol + wx * (BN / 2) + n * 16 + (lane & 15);
            float bv = bias[col];
#pragma unroll
            for (int j = 0; j < 4; ++j) {
                int row = row0 + j;
                float v = acc[m][n][j] + bv;
                if constexpr (EPI == 0) {
                    actOut[(size_t)row * HID + col] = f2bf(fast_tanh(v));
                } else {
                    size_t idx = (size_t)row * DIM + col;
                    float yb = pyb[m][n][j];
                    if constexpr (EPI == 1) {
                        accum[idx] = v;
                        ybf[idx] = f2bf(yb + 0.5f * dtv * v);
                    } else if constexpr (EPI == 2) {
                        accum[idx] = pac[m][n][j] + 2.0f * v;
                        ybf[idx] = f2bf(yb + 0.5f * dtv * v);
                    } else if constexpr (EPI == 3) {
                        accum[idx] = pac[m][n][j] + 2.0f * v;
                        ybf[idx] = f2bf(yb + dtv * v);
                    } else {  // EPI == 4
                        float yn = yb + (dtv * (1.0f / 6.0f)) * (pac[m][n][j] + v);
                        ynext[idx] = yn;
                        ybf[idx] = f2bf(yn);
                    }
                }
            }
        }
    }
}

extern "C" void kernel_launch(void* const* d_in, const int* in_sizes, int n_in,
                              void* d_out, int out_size, void* d_ws, size_t ws_size,
                              hipStream_t stream) {
    (void)in_sizes; (void)n_in; (void)out_size; (void)ws_size;
    const float* x0 = (const float*)d_in[0];
    const float* t  = (const float*)d_in[1];
    const float* W1 = (const float*)d_in[2];
    const float* b1 = (const float*)d_in[3];
    const float* W2 = (const float*)d_in[4];
    const float* b2 = (const float*)d_in[5];
    float* out = (float*)d_out;

    char* ws = (char*)d_ws;
    u16*   ybf   = (u16*)  (ws);               //  4 MB  [4096,512]  bf16
    u16*   act   = (u16*)  (ws + (4u  << 20)); //  8 MB  [4096,1024] bf16
    float* accum = (float*)(ws + (12u << 20)); //  8 MB  [4096,512]  f32
    u16*   W1T   = (u16*)  (ws + (20u << 20)); //  1 MB  [1024,512]  bf16
    u16*   W2T   = (u16*)  (ws + (21u << 20)); //  1 MB  [512,1024]  bf16

    init_state<<<(BATCH * DIM + 255) / 256, 256, 0, stream>>>(x0, out, ybf, BATCH * DIM);
    transpose_convert<<<dim3(HID / 32, DIM / 8), dim3(32, 8), 0, stream>>>(W1, W1T, DIM, HID);
    transpose_convert<<<dim3(DIM / 32, HID / 8), dim3(32, 8), 0, stream>>>(W2, W2T, HID, DIM);

    dim3 blk(256);
    dim3 g1(BATCH / 128, HID / 64);    // 32 x 16 = 512 blocks (2 per CU)
    dim3 g2(BATCH / 64,  DIM / 64);    // 64 x 8  = 512 blocks (2 per CU)

    for (int s = 0; s < TSTEPS - 1; ++s) {
        const float* yb_s = out + (size_t)s * BATCH * DIM;
        float*       yn_s = out + (size_t)(s + 1) * BATCH * DIM;

        // stage 1: k1 = f(y)
        gemm_bt<128,64,0,2><<<g1, blk, 0, stream>>>(ybf, W1T, b1, BATCH, HID, DIM,
                                                    act, nullptr, nullptr, nullptr, nullptr, nullptr, 0);
        gemm_bt<64,64,1,3><<<g2, blk, 0, stream>>>(act, W2T, b2, BATCH, DIM, HID,
                                                   nullptr, yb_s, yn_s, accum, ybf, t, s);
        // stage 2: k2 = f(y + dt/2 * k1)
        gemm_bt<128,64,0,2><<<g1, blk, 0, stream>>>(ybf, W1T, b1, BATCH, HID, DIM,
                                                    act, nullptr, nullptr, nullptr, nullptr, nullptr, 0);
        gemm_bt<64,64,2,3><<<g2, blk, 0, stream>>>(act, W2T, b2, BATCH, DIM, HID,
                                                   nullptr, yb_s, yn_s, accum, ybf, t, s);
        // stage 3: k3 = f(y + dt/2 * k2)
        gemm_bt<128,64,0,2><<<g1, blk, 0, stream>>>(ybf, W1T, b1, BATCH, HID, DIM,
                                                    act, nullptr, nullptr, nullptr, nullptr, nullptr, 0);
        gemm_bt<64,64,3,3><<<g2, blk, 0, stream>>>(act, W2T, b2, BATCH, DIM, HID,
                                                   nullptr, yb_s, yn_s, accum, ybf, t, s);
        // stage 4: y' = y + dt/6 * (k1 + 2k2 + 2k3 + k4)
        gemm_bt<128,64,0,2><<<g1, blk, 0, stream>>>(ybf, W1T, b1, BATCH, HID, DIM,
                                                    act, nullptr, nullptr, nullptr, nullptr, nullptr, 0);
        gemm_bt<64,64,4,3><<<g2, blk, 0, stream>>>(act, W2T, b2, BATCH, DIM, HID,
                                                   nullptr, yb_s, yn_s, accum, ybf, t, s);
    }
}

// Round 20
// 1683.658 us; speedup vs baseline: 1.0879x; 1.0559x over previous
//
// R20 = R17 + XCD-affinity swizzle for GEMM2 (act/ybf exchanges become XCD-local L2 hits)
#include <hip/hip_runtime.h>
#include <hip/hip_bf16.h>
#include <cstdint>

#define BATCH 4096
#define DIM   512
#define HID   1024
#define TSTEPS 20

typedef unsigned short u16;
typedef short s16x8 __attribute__((ext_vector_type(8)));
typedef float f32x4 __attribute__((ext_vector_type(4)));

__device__ __forceinline__ u16 f2bf(float f) {
    unsigned int u = __float_as_uint(f);
    u = (u + 0x7FFFu + ((u >> 16) & 1u)) >> 16;   // RNE
    return (u16)u;
}

__device__ __forceinline__ float fast_tanh(float x) {
    float ax = __builtin_fabsf(x);
    float e  = __expf(2.0f * ax);                 // inf for large ax -> t = 1
    float t  = 1.0f - 2.0f * __builtin_amdgcn_rcpf(e + 1.0f);
    return __builtin_copysignf(t, x);
}

// out[0] = x0 ; ybf = bf16(x0)
__global__ void init_state(const float* __restrict__ x0, float* __restrict__ out0,
                           u16* __restrict__ ybf, int n) {
    int i = blockIdx.x * blockDim.x + threadIdx.x;
    if (i < n) { float v = x0[i]; out0[i] = v; ybf[i] = f2bf(v); }
}

// Wt[n*K + k] = bf16(W[k*N + n])   (W is [K][N] row-major)
__global__ void transpose_convert(const float* __restrict__ W, u16* __restrict__ Wt,
                                  int K, int N) {
    int n = blockIdx.x * 32 + threadIdx.x;
    int k = blockIdx.y * 8  + threadIdx.y;
    if (n < N && k < K) Wt[(size_t)n * K + k] = f2bf(W[(size_t)k * N + n]);
}

// C = A[M,K] * Bt[N,K]^T, fused epilogue. (DEPTH+1)-buffer depth-DEPTH pipelined
// K-loop, counted vmcnt, ONE barrier per iteration (WAR covered by next top barrier).
// EPI==0 : act = bf16(fast_tanh(C + bias))      (GEMM1, native 2D grid)
// EPI==1..4 : RK4 stage epilogues               (GEMM2, 1D grid + XCD-affinity swizzle:
//   rows [bx2*64) land on XCD (bx2>>1)%8 == the XCD that produced act rows / consumes ybf rows)
template<int BM, int BN, int EPI, int DEPTH>
__global__ __launch_bounds__(256, 2) void gemm_bt(
    const u16* __restrict__ A,
    const u16* __restrict__ Bt,
    const float* __restrict__ bias,
    int M, int N, int K,
    u16* __restrict__ actOut,
    const float* __restrict__ ybase,
    float* __restrict__ ynext,
    float* __restrict__ accum,
    u16* __restrict__ ybf,
    const float* __restrict__ tgrid, int step)
{
    constexpr int AC = BM / 8;          // A chunks (1 KiB each) per K-tile
    constexpr int BC = BN / 8;
    constexpr int CPW = (AC + BC) / 4;  // global_load_lds per thread per tile
    constexpr int NBUF = DEPTH + 1;
    static_assert((DEPTH == 2 && CPW == 6) || (DEPTH == 3 && CPW == 4),
                  "vmcnt literals below assume these configs");
    constexpr int WM = BM / 32;
    constexpr int WN = BN / 32;
    constexpr int BUFE = (BM + BN) * 64;   // u16 elems per LDS buffer

    __shared__ u16 lds[NBUF * BUFE];

    const int tid  = threadIdx.x;
    const int lane = tid & 63;
    const int wid  = tid >> 6;
    const int wy   = wid >> 1;
    const int wx   = wid & 1;

    // block -> tile mapping
    int bxv, byv;
    if constexpr (EPI == 0) {
        bxv = blockIdx.x; byv = blockIdx.y;
    } else {
        // bijective XCD-affinity decode: lin%8 selects XCD; row128-group ≡ XCD (mod 8)
        int lin  = blockIdx.x;          // [0, 512)
        int xcd  = lin & 7;
        int j    = lin >> 3;            // [0, 64)
        byv      = j & 7;
        int rest = j >> 3;              // [0, 8)
        bxv      = (xcd + 8 * (rest >> 1)) * 2 + (rest & 1);   // [0, 64)
    }
    const int brow = bxv * BM;
    const int bcol = byv * BN;

    const int srow = lane >> 3;                    // row within 8-row group
    const int scol = ((lane & 7) ^ srow) * 8;      // pre-swizzled k offset (elems)

    f32x4 acc[WM][WN];
#pragma unroll
    for (int m = 0; m < WM; ++m)
#pragma unroll
        for (int n = 0; n < WN; ++n)
            acc[m][n] = (f32x4){0.f, 0.f, 0.f, 0.f};

    auto stage = [&](int buf, int kt) {
        const int k0 = kt * 64;
        u16* base = &lds[buf * BUFE];
#pragma unroll
        for (int c0 = 0; c0 < CPW; ++c0) {
            int c = wid * CPW + c0;            // wave-uniform
            if (c < AC) {
                int row = c * 8 + srow;
                const u16* g = A + (size_t)(brow + row) * K + k0 + scol;
                __builtin_amdgcn_global_load_lds(
                    (const __attribute__((address_space(1))) unsigned int*)g,
                    (__attribute__((address_space(3))) unsigned int*)&base[c * 512],
                    16, 0, 0);
            } else {
                int cb = c - AC;
                int row = cb * 8 + srow;
                const u16* g = Bt + (size_t)(bcol + row) * K + k0 + scol;
                __builtin_amdgcn_global_load_lds(
                    (const __attribute__((address_space(1))) unsigned int*)g,
                    (__attribute__((address_space(3))) unsigned int*)&base[BM * 64 + cb * 512],
                    16, 0, 0);
            }
        }
    };

    const int NT = K / 64;

    // prologue: DEPTH tiles in flight
#pragma unroll
    for (int d = 0; d < DEPTH; ++d) stage(d, d);

    for (int kt = 0; kt < NT; ++kt) {
        // wait until tile kt's loads complete; keep later tiles in flight
        if constexpr (DEPTH == 2) {
            if (kt < NT - 1) asm volatile("s_waitcnt vmcnt(6)" ::: "memory");
            else             asm volatile("s_waitcnt vmcnt(0)" ::: "memory");
        } else {
            if (kt < NT - 2)       asm volatile("s_waitcnt vmcnt(8)" ::: "memory");
            else if (kt == NT - 2) asm volatile("s_waitcnt vmcnt(4)" ::: "memory");
            else                   asm volatile("s_waitcnt vmcnt(0)" ::: "memory");
        }
        // single barrier: all waves' tile-kt loads landed; also seals WAR for the
        // buffer staged below (last read by all waves in iter kt-1).
        __builtin_amdgcn_s_barrier();

        const char* lb = (const char*)&lds[(kt % NBUF) * BUFE];

        s16x8 af[2][WM], bfr[2][WN];
#pragma unroll
        for (int ks = 0; ks < 2; ++ks) {
#pragma unroll
            for (int m = 0; m < WM; ++m) {
                int row = wy * (BM / 2) + m * 16 + (lane & 15);
                unsigned byte = (unsigned)(row * 128 + (ks * 32 + (lane >> 4) * 8) * 2);
                byte ^= (unsigned)((row & 7) << 4);
                af[ks][m] = *(const s16x8*)(lb + byte);
            }
#pragma unroll
            for (int n = 0; n < WN; ++n) {
                int row = wx * (BN / 2) + n * 16 + (lane & 15);
                unsigned byte = (unsigned)(BM * 128 + row * 128 + (ks * 32 + (lane >> 4) * 8) * 2);
                byte ^= (unsigned)((row & 7) << 4);
                bfr[ks][n] = *(const s16x8*)(lb + byte);
            }
        }

        // issue tile kt+DEPTH while tile kt computes
        if (kt + DEPTH < NT) stage((kt + DEPTH) % NBUF, kt + DEPTH);

#pragma unroll
        for (int ks = 0; ks < 2; ++ks)
#pragma unroll
            for (int m = 0; m < WM; ++m)
#pragma unroll
                for (int n = 0; n < WN; ++n)
                    acc[m][n] = __builtin_amdgcn_mfma_f32_16x16x32_bf16(
                        af[ks][m], bfr[ks][n], acc[m][n], 0, 0, 0);
    }

    // ---- epilogue ----
    float dtv = 0.f;
    if constexpr (EPI >= 1) dtv = tgrid[step + 1] - tgrid[step];

#pragma unroll
    for (int m = 0; m < WM; ++m) {
        int row0 = brow + wy * (BM / 2) + m * 16 + (lane >> 4) * 4;
#pragma unroll
        for (int n = 0; n < WN; ++n) {
            int col = bcol + wx * (BN / 2) + n * 16 + (lane & 15);
            float bv = bias[col];
#pragma unroll
            for (int j = 0; j < 4; ++j) {
                int row = row0 + j;
                float v = acc[m][n][j] + bv;
                if constexpr (EPI == 0) {
                    actOut[(size_t)row * HID + col] = f2bf(fast_tanh(v));
                } else {
                    size_t idx = (size_t)row * DIM + col;
                    float yb = ybase[idx];
                    if constexpr (EPI == 1) {
                        accum[idx] = v;
                        ybf[idx] = f2bf(yb + 0.5f * dtv * v);
                    } else if constexpr (EPI == 2) {
                        accum[idx] += 2.0f * v;
                        ybf[idx] = f2bf(yb + 0.5f * dtv * v);
                    } else if constexpr (EPI == 3) {
                        accum[idx] += 2.0f * v;
                        ybf[idx] = f2bf(yb + dtv * v);
                    } else {  // EPI == 4
                        float yn = yb + (dtv * (1.0f / 6.0f)) * (accum[idx] + v);
                        ynext[idx] = yn;
                        ybf[idx] = f2bf(yn);
                    }
                }
            }
        }
    }
}

extern "C" void kernel_launch(void* const* d_in, const int* in_sizes, int n_in,
                              void* d_out, int out_size, void* d_ws, size_t ws_size,
                              hipStream_t stream) {
    (void)in_sizes; (void)n_in; (void)out_size; (void)ws_size;
    const float* x0 = (const float*)d_in[0];
    const float* t  = (const float*)d_in[1];
    const float* W1 = (const float*)d_in[2];
    const float* b1 = (const float*)d_in[3];
    const float* W2 = (const float*)d_in[4];
    const float* b2 = (const float*)d_in[5];
    float* out = (float*)d_out;

    char* ws = (char*)d_ws;
    u16*   ybf   = (u16*)  (ws);               //  4 MB  [4096,512]  bf16
    u16*   act   = (u16*)  (ws + (4u  << 20)); //  8 MB  [4096,1024] bf16
    float* accum = (float*)(ws + (12u << 20)); //  8 MB  [4096,512]  f32
    u16*   W1T   = (u16*)  (ws + (20u << 20)); //  1 MB  [1024,512]  bf16
    u16*   W2T   = (u16*)  (ws + (21u << 20)); //  1 MB  [512,1024]  bf16

    init_state<<<(BATCH * DIM + 255) / 256, 256, 0, stream>>>(x0, out, ybf, BATCH * DIM);
    transpose_convert<<<dim3(HID / 32, DIM / 8), dim3(32, 8), 0, stream>>>(W1, W1T, DIM, HID);
    transpose_convert<<<dim3(DIM / 32, HID / 8), dim3(32, 8), 0, stream>>>(W2, W2T, HID, DIM);

    dim3 blk(256);
    dim3 g1(BATCH / 128, HID / 64);    // 32 x 16 = 512 blocks (2 per CU)
    dim3 g2(512);                      // 1D, XCD-affinity decoded in-kernel

    for (int s = 0; s < TSTEPS - 1; ++s) {
        const float* yb_s = out + (size_t)s * BATCH * DIM;
        float*       yn_s = out + (size_t)(s + 1) * BATCH * DIM;

        // stage 1: k1 = f(y)
        gemm_bt<128,64,0,2><<<g1, blk, 0, stream>>>(ybf, W1T, b1, BATCH, HID, DIM,
                                                    act, nullptr, nullptr, nullptr, nullptr, nullptr, 0);
        gemm_bt<64,64,1,3><<<g2, blk, 0, stream>>>(act, W2T, b2, BATCH, DIM, HID,
                                                   nullptr, yb_s, yn_s, accum, ybf, t, s);
        // stage 2: k2 = f(y + dt/2 * k1)
        gemm_bt<128,64,0,2><<<g1, blk, 0, stream>>>(ybf, W1T, b1, BATCH, HID, DIM,
                                                    act, nullptr, nullptr, nullptr, nullptr, nullptr, 0);
        gemm_bt<64,64,2,3><<<g2, blk, 0, stream>>>(act, W2T, b2, BATCH, DIM, HID,
                                                   nullptr, yb_s, yn_s, accum, ybf, t, s);
        // stage 3: k3 = f(y + dt/2 * k2)
        gemm_bt<128,64,0,2><<<g1, blk, 0, stream>>>(ybf, W1T, b1, BATCH, HID, DIM,
                                                    act, nullptr, nullptr, nullptr, nullptr, nullptr, 0);
        gemm_bt<64,64,3,3><<<g2, blk, 0, stream>>>(act, W2T, b2, BATCH, DIM, HID,
                                                   nullptr, yb_s, yn_s, accum, ybf, t, s);
        // stage 4: y' = y + dt/6 * (k1 + 2k2 + 2k3 + k4)
        gemm_bt<128,64,0,2><<<g1, blk, 0, stream>>>(ybf, W1T, b1, BATCH, HID, DIM,
                                                    act, nullptr, nullptr, nullptr, nullptr, nullptr, 0);
        gemm_bt<64,64,4,3><<<g2, blk, 0, stream>>>(act, W2T, b2, BATCH, DIM, HID,
                                                   nullptr, yb_s, yn_s, accum, ybf, t, s);
    }
}

// Round 21
// 1681.615 us; speedup vs baseline: 1.0892x; 1.0012x over previous
//
// R21 = R20 with accum folded into ynext (running RK4 accumulation in the out slot;
// accum array deleted -> per-XCD hot set fits L2; st3 drops the yb read)
#include <hip/hip_runtime.h>
#include <hip/hip_bf16.h>
#include <cstdint>

#define BATCH 4096
#define DIM   512
#define HID   1024
#define TSTEPS 20

typedef unsigned short u16;
typedef short s16x8 __attribute__((ext_vector_type(8)));
typedef float f32x4 __attribute__((ext_vector_type(4)));

__device__ __forceinline__ u16 f2bf(float f) {
    unsigned int u = __float_as_uint(f);
    u = (u + 0x7FFFu + ((u >> 16) & 1u)) >> 16;   // RNE
    return (u16)u;
}

__device__ __forceinline__ float fast_tanh(float x) {
    float ax = __builtin_fabsf(x);
    float e  = __expf(2.0f * ax);                 // inf for large ax -> t = 1
    float t  = 1.0f - 2.0f * __builtin_amdgcn_rcpf(e + 1.0f);
    return __builtin_copysignf(t, x);
}

// out[0] = x0 ; ybf = bf16(x0)
__global__ void init_state(const float* __restrict__ x0, float* __restrict__ out0,
                           u16* __restrict__ ybf, int n) {
    int i = blockIdx.x * blockDim.x + threadIdx.x;
    if (i < n) { float v = x0[i]; out0[i] = v; ybf[i] = f2bf(v); }
}

// Wt[n*K + k] = bf16(W[k*N + n])   (W is [K][N] row-major)
__global__ void transpose_convert(const float* __restrict__ W, u16* __restrict__ Wt,
                                  int K, int N) {
    int n = blockIdx.x * 32 + threadIdx.x;
    int k = blockIdx.y * 8  + threadIdx.y;
    if (n < N && k < K) Wt[(size_t)n * K + k] = f2bf(W[(size_t)k * N + n]);
}

// C = A[M,K] * Bt[N,K]^T, fused epilogue. (DEPTH+1)-buffer depth-DEPTH pipelined
// K-loop, counted vmcnt, ONE barrier per iteration (WAR covered by next top barrier).
// EPI==0 : act = bf16(fast_tanh(C + bias))      (GEMM1, native 2D grid)
// EPI==1..4 : RK4 stage epilogues, running accumulation into ynext:
//   st0: yn = yb + (dt/6)k1 ; ybf = bf16(yb + dt/2 k1)
//   st1: yn += (dt/3)k2     ; ybf = bf16(yb + dt/2 k2)
//   st2: yn += (dt/3)k3     ; ybf = bf16(yb + dt   k3)
//   st3: yn += (dt/6)k4     ; ybf = bf16(yn)           (no yb read)
// GEMM2 uses a 1D grid + XCD-affinity swizzle (rows land on their producer XCD).
template<int BM, int BN, int EPI, int DEPTH>
__global__ __launch_bounds__(256, 2) void gemm_bt(
    const u16* __restrict__ A,
    const u16* __restrict__ Bt,
    const float* __restrict__ bias,
    int M, int N, int K,
    u16* __restrict__ actOut,
    const float* __restrict__ ybase,
    float* __restrict__ ynext,
    u16* __restrict__ ybf,
    const float* __restrict__ tgrid, int step)
{
    constexpr int AC = BM / 8;          // A chunks (1 KiB each) per K-tile
    constexpr int BC = BN / 8;
    constexpr int CPW = (AC + BC) / 4;  // global_load_lds per thread per tile
    constexpr int NBUF = DEPTH + 1;
    static_assert((DEPTH == 2 && CPW == 6) || (DEPTH == 3 && CPW == 4),
                  "vmcnt literals below assume these configs");
    constexpr int WM = BM / 32;
    constexpr int WN = BN / 32;
    constexpr int BUFE = (BM + BN) * 64;   // u16 elems per LDS buffer

    __shared__ u16 lds[NBUF * BUFE];

    const int tid  = threadIdx.x;
    const int lane = tid & 63;
    const int wid  = tid >> 6;
    const int wy   = wid >> 1;
    const int wx   = wid & 1;

    // block -> tile mapping
    int bxv, byv;
    if constexpr (EPI == 0) {
        bxv = blockIdx.x; byv = blockIdx.y;
    } else {
        // bijective XCD-affinity decode: lin%8 selects XCD; row128-group ≡ XCD (mod 8)
        int lin  = blockIdx.x;          // [0, 512)
        int xcd  = lin & 7;
        int j    = lin >> 3;            // [0, 64)
        byv      = j & 7;
        int rest = j >> 3;              // [0, 8)
        bxv      = (xcd + 8 * (rest >> 1)) * 2 + (rest & 1);   // [0, 64)
    }
    const int brow = bxv * BM;
    const int bcol = byv * BN;

    const int srow = lane >> 3;                    // row within 8-row group
    const int scol = ((lane & 7) ^ srow) * 8;      // pre-swizzled k offset (elems)

    f32x4 acc[WM][WN];
#pragma unroll
    for (int m = 0; m < WM; ++m)
#pragma unroll
        for (int n = 0; n < WN; ++n)
            acc[m][n] = (f32x4){0.f, 0.f, 0.f, 0.f};

    auto stage = [&](int buf, int kt) {
        const int k0 = kt * 64;
        u16* base = &lds[buf * BUFE];
#pragma unroll
        for (int c0 = 0; c0 < CPW; ++c0) {
            int c = wid * CPW + c0;            // wave-uniform
            if (c < AC) {
                int row = c * 8 + srow;
                const u16* g = A + (size_t)(brow + row) * K + k0 + scol;
                __builtin_amdgcn_global_load_lds(
                    (const __attribute__((address_space(1))) unsigned int*)g,
                    (__attribute__((address_space(3))) unsigned int*)&base[c * 512],
                    16, 0, 0);
            } else {
                int cb = c - AC;
                int row = cb * 8 + srow;
                const u16* g = Bt + (size_t)(bcol + row) * K + k0 + scol;
                __builtin_amdgcn_global_load_lds(
                    (const __attribute__((address_space(1))) unsigned int*)g,
                    (__attribute__((address_space(3))) unsigned int*)&base[BM * 64 + cb * 512],
                    16, 0, 0);
            }
        }
    };

    const int NT = K / 64;

    // prologue: DEPTH tiles in flight
#pragma unroll
    for (int d = 0; d < DEPTH; ++d) stage(d, d);

    for (int kt = 0; kt < NT; ++kt) {
        // wait until tile kt's loads complete; keep later tiles in flight
        if constexpr (DEPTH == 2) {
            if (kt < NT - 1) asm volatile("s_waitcnt vmcnt(6)" ::: "memory");
            else             asm volatile("s_waitcnt vmcnt(0)" ::: "memory");
        } else {
            if (kt < NT - 2)       asm volatile("s_waitcnt vmcnt(8)" ::: "memory");
            else if (kt == NT - 2) asm volatile("s_waitcnt vmcnt(4)" ::: "memory");
            else                   asm volatile("s_waitcnt vmcnt(0)" ::: "memory");
        }
        // single barrier: all waves' tile-kt loads landed; also seals WAR for the
        // buffer staged below (last read by all waves in iter kt-1).
        __builtin_amdgcn_s_barrier();

        const char* lb = (const char*)&lds[(kt % NBUF) * BUFE];

        s16x8 af[2][WM], bfr[2][WN];
#pragma unroll
        for (int ks = 0; ks < 2; ++ks) {
#pragma unroll
            for (int m = 0; m < WM; ++m) {
                int row = wy * (BM / 2) + m * 16 + (lane & 15);
                unsigned byte = (unsigned)(row * 128 + (ks * 32 + (lane >> 4) * 8) * 2);
                byte ^= (unsigned)((row & 7) << 4);
                af[ks][m] = *(const s16x8*)(lb + byte);
            }
#pragma unroll
            for (int n = 0; n < WN; ++n) {
                int row = wx * (BN / 2) + n * 16 + (lane & 15);
                unsigned byte = (unsigned)(BM * 128 + row * 128 + (ks * 32 + (lane >> 4) * 8) * 2);
                byte ^= (unsigned)((row & 7) << 4);
                bfr[ks][n] = *(const s16x8*)(lb + byte);
            }
        }

        // issue tile kt+DEPTH while tile kt computes
        if (kt + DEPTH < NT) stage((kt + DEPTH) % NBUF, kt + DEPTH);

#pragma unroll
        for (int ks = 0; ks < 2; ++ks)
#pragma unroll
            for (int m = 0; m < WM; ++m)
#pragma unroll
                for (int n = 0; n < WN; ++n)
                    acc[m][n] = __builtin_amdgcn_mfma_f32_16x16x32_bf16(
                        af[ks][m], bfr[ks][n], acc[m][n], 0, 0, 0);
    }

    // ---- epilogue ----
    float dtv = 0.f;
    if constexpr (EPI >= 1) dtv = tgrid[step + 1] - tgrid[step];

#pragma unroll
    for (int m = 0; m < WM; ++m) {
        int row0 = brow + wy * (BM / 2) + m * 16 + (lane >> 4) * 4;
#pragma unroll
        for (int n = 0; n < WN; ++n) {
            int col = bcol + wx * (BN / 2) + n * 16 + (lane & 15);
            float bv = bias[col];
#pragma unroll
            for (int j = 0; j < 4; ++j) {
                int row = row0 + j;
                float v = acc[m][n][j] + bv;
                if constexpr (EPI == 0) {
                    actOut[(size_t)row * HID + col] = f2bf(fast_tanh(v));
                } else {
                    size_t idx = (size_t)row * DIM + col;
                    if constexpr (EPI == 1) {
                        float yb = ybase[idx];
                        ynext[idx] = yb + (dtv * (1.0f / 6.0f)) * v;
                        ybf[idx] = f2bf(yb + 0.5f * dtv * v);
                    } else if constexpr (EPI == 2) {
                        float yb = ybase[idx];
                        ynext[idx] += (dtv * (1.0f / 3.0f)) * v;
                        ybf[idx] = f2bf(yb + 0.5f * dtv * v);
                    } else if constexpr (EPI == 3) {
                        float yb = ybase[idx];
                        ynext[idx] += (dtv * (1.0f / 3.0f)) * v;
                        ybf[idx] = f2bf(yb + dtv * v);
                    } else {  // EPI == 4
                        float yn = ynext[idx] + (dtv * (1.0f / 6.0f)) * v;
                        ynext[idx] = yn;
                        ybf[idx] = f2bf(yn);
                    }
                }
            }
        }
    }
}

extern "C" void kernel_launch(void* const* d_in, const int* in_sizes, int n_in,
                              void* d_out, int out_size, void* d_ws, size_t ws_size,
                              hipStream_t stream) {
    (void)in_sizes; (void)n_in; (void)out_size; (void)ws_size;
    const float* x0 = (const float*)d_in[0];
    const float* t  = (const float*)d_in[1];
    const float* W1 = (const float*)d_in[2];
    const float* b1 = (const float*)d_in[3];
    const float* W2 = (const float*)d_in[4];
    const float* b2 = (const float*)d_in[5];
    float* out = (float*)d_out;

    char* ws = (char*)d_ws;
    u16*   ybf   = (u16*)  (ws);               //  4 MB  [4096,512]  bf16
    u16*   act   = (u16*)  (ws + (4u  << 20)); //  8 MB  [4096,1024] bf16
    u16*   W1T   = (u16*)  (ws + (12u << 20)); //  1 MB  [1024,512]  bf16
    u16*   W2T   = (u16*)  (ws + (13u << 20)); //  1 MB  [512,1024]  bf16

    init_state<<<(BATCH * DIM + 255) / 256, 256, 0, stream>>>(x0, out, ybf, BATCH * DIM);
    transpose_convert<<<dim3(HID / 32, DIM / 8), dim3(32, 8), 0, stream>>>(W1, W1T, DIM, HID);
    transpose_convert<<<dim3(DIM / 32, HID / 8), dim3(32, 8), 0, stream>>>(W2, W2T, HID, DIM);

    dim3 blk(256);
    dim3 g1(BATCH / 128, HID / 64);    // 32 x 16 = 512 blocks (2 per CU)
    dim3 g2(512);                      // 1D, XCD-affinity decoded in-kernel

    for (int s = 0; s < TSTEPS - 1; ++s) {
        const float* yb_s = out + (size_t)s * BATCH * DIM;
        float*       yn_s = out + (size_t)(s + 1) * BATCH * DIM;

        // stage 1: k1 = f(y)
        gemm_bt<128,64,0,2><<<g1, blk, 0, stream>>>(ybf, W1T, b1, BATCH, HID, DIM,
                                                    act, nullptr, nullptr, nullptr, nullptr, 0);
        gemm_bt<64,64,1,3><<<g2, blk, 0, stream>>>(act, W2T, b2, BATCH, DIM, HID,
                                                   nullptr, yb_s, yn_s, ybf, t, s);
        // stage 2: k2 = f(y + dt/2 * k1)
        gemm_bt<128,64,0,2><<<g1, blk, 0, stream>>>(ybf, W1T, b1, BATCH, HID, DIM,
                                                    act, nullptr, nullptr, nullptr, nullptr, 0);
        gemm_bt<64,64,2,3><<<g2, blk, 0, stream>>>(act, W2T, b2, BATCH, DIM, HID,
                                                   nullptr, yb_s, yn_s, ybf, t, s);
        // stage 3: k3 = f(y + dt/2 * k2)
        gemm_bt<128,64,0,2><<<g1, blk, 0, stream>>>(ybf, W1T, b1, BATCH, HID, DIM,
                                                    act, nullptr, nullptr, nullptr, nullptr, 0);
        gemm_bt<64,64,3,3><<<g2, blk, 0, stream>>>(act, W2T, b2, BATCH, DIM, HID,
                                                   nullptr, yb_s, yn_s, ybf, t, s);
        // stage 4: y' = y + dt/6 * (k1 + 2k2 + 2k3 + k4)
        gemm_bt<128,64,0,2><<<g1, blk, 0, stream>>>(ybf, W1T, b1, BATCH, HID, DIM,
                                                    act, nullptr, nullptr, nullptr, nullptr, 0);
        gemm_bt<64,64,4,3><<<g2, blk, 0, stream>>>(act, W2T, b2, BATCH, DIM, HID,
                                                   nullptr, yb_s, yn_s, ybf, t, s);
    }
}

// Round 22
// 1660.058 us; speedup vs baseline: 1.1034x; 1.0130x over previous
//
// R22 = R21 with GEMM1 as 8-wave 128x128 blocks (grid 256, half the per-launch
// overhead instances + half the A staging); GEMM2 unchanged (verified 64x64/4-wave)
#include <hip/hip_runtime.h>
#include <hip/hip_bf16.h>
#include <cstdint>

#define BATCH 4096
#define DIM   512
#define HID   1024
#define TSTEPS 20

typedef unsigned short u16;
typedef short s16x8 __attribute__((ext_vector_type(8)));
typedef float f32x4 __attribute__((ext_vector_type(4)));

__device__ __forceinline__ u16 f2bf(float f) {
    unsigned int u = __float_as_uint(f);
    u = (u + 0x7FFFu + ((u >> 16) & 1u)) >> 16;   // RNE
    return (u16)u;
}

__device__ __forceinline__ float fast_tanh(float x) {
    float ax = __builtin_fabsf(x);
    float e  = __expf(2.0f * ax);                 // inf for large ax -> t = 1
    float t  = 1.0f - 2.0f * __builtin_amdgcn_rcpf(e + 1.0f);
    return __builtin_copysignf(t, x);
}

// out[0] = x0 ; ybf = bf16(x0)
__global__ void init_state(const float* __restrict__ x0, float* __restrict__ out0,
                           u16* __restrict__ ybf, int n) {
    int i = blockIdx.x * blockDim.x + threadIdx.x;
    if (i < n) { float v = x0[i]; out0[i] = v; ybf[i] = f2bf(v); }
}

// Wt[n*K + k] = bf16(W[k*N + n])   (W is [K][N] row-major)
__global__ void transpose_convert(const float* __restrict__ W, u16* __restrict__ Wt,
                                  int K, int N) {
    int n = blockIdx.x * 32 + threadIdx.x;
    int k = blockIdx.y * 8  + threadIdx.y;
    if (n < N && k < K) Wt[(size_t)n * K + k] = f2bf(W[(size_t)k * N + n]);
}

// C = A[M,K] * Bt[N,K]^T, fused epilogue. (DEPTH+1)-buffer depth-DEPTH pipelined
// K-loop, counted vmcnt, ONE barrier per iteration. Wave grid = 2 rows x (WAVES/2) cols.
// EPI==0 : act = bf16(fast_tanh(C + bias))      (GEMM1, native 2D grid)
// EPI==1..4 : RK4 running-accumulation epilogues (GEMM2, 1D grid + XCD-affinity swizzle)
template<int BM, int BN, int EPI, int DEPTH, int WAVES>
__global__ __launch_bounds__(WAVES * 64, (WAVES == 4) ? 2 : 1) void gemm_bt(
    const u16* __restrict__ A,
    const u16* __restrict__ Bt,
    const float* __restrict__ bias,
    int M, int N, int K,
    u16* __restrict__ actOut,
    const float* __restrict__ ybase,
    float* __restrict__ ynext,
    u16* __restrict__ ybf,
    const float* __restrict__ tgrid, int step)
{
    constexpr int AC = BM / 8;          // A chunks (1 KiB each) per K-tile
    constexpr int BC = BN / 8;
    constexpr int CPW = (AC + BC) / WAVES;  // global_load_lds per thread per tile
    constexpr int NBUF = DEPTH + 1;
    static_assert((DEPTH == 2 && (CPW == 6 || CPW == 4)) || (DEPTH == 3 && CPW == 4),
                  "vmcnt literals below assume these configs");
    constexpr int WCOLS = WAVES / 2;    // wave grid: 2 rows x WCOLS cols
    constexpr int WM = BM / 32;         // 16x16 frags per wave (rows; 2 wave-rows)
    constexpr int WN = BN / (16 * WCOLS);
    constexpr int BUFE = (BM + BN) * 64;   // u16 elems per LDS buffer

    __shared__ u16 lds[NBUF * BUFE];

    const int tid  = threadIdx.x;
    const int lane = tid & 63;
    const int wid  = tid >> 6;
    const int wy   = wid / WCOLS;       // 0..1
    const int wx   = wid % WCOLS;       // 0..WCOLS-1

    // block -> tile mapping
    int bxv, byv;
    if constexpr (EPI == 0) {
        bxv = blockIdx.x; byv = blockIdx.y;
    } else {
        // bijective XCD-affinity decode: lin%8 selects XCD; row128-group ≡ XCD (mod 8)
        int lin  = blockIdx.x;          // [0, 512)
        int xcd  = lin & 7;
        int j    = lin >> 3;            // [0, 64)
        byv      = j & 7;
        int rest = j >> 3;              // [0, 8)
        bxv      = (xcd + 8 * (rest >> 1)) * 2 + (rest & 1);   // [0, 64)
    }
    const int brow = bxv * BM;
    const int bcol = byv * BN;

    const int srow = lane >> 3;                    // row within 8-row group
    const int scol = ((lane & 7) ^ srow) * 8;      // pre-swizzled k offset (elems)

    f32x4 acc[WM][WN];
#pragma unroll
    for (int m = 0; m < WM; ++m)
#pragma unroll
        for (int n = 0; n < WN; ++n)
            acc[m][n] = (f32x4){0.f, 0.f, 0.f, 0.f};

    auto stage = [&](int buf, int kt) {
        const int k0 = kt * 64;
        u16* base = &lds[buf * BUFE];
#pragma unroll
        for (int c0 = 0; c0 < CPW; ++c0) {
            int c = wid * CPW + c0;            // wave-uniform
            if (c < AC) {
                int row = c * 8 + srow;
                const u16* g = A + (size_t)(brow + row) * K + k0 + scol;
                __builtin_amdgcn_global_load_lds(
                    (const __attribute__((address_space(1))) unsigned int*)g,
                    (__attribute__((address_space(3))) unsigned int*)&base[c * 512],
                    16, 0, 0);
            } else {
                int cb = c - AC;
                int row = cb * 8 + srow;
                const u16* g = Bt + (size_t)(bcol + row) * K + k0 + scol;
                __builtin_amdgcn_global_load_lds(
                    (const __attribute__((address_space(1))) unsigned int*)g,
                    (__attribute__((address_space(3))) unsigned int*)&base[BM * 64 + cb * 512],
                    16, 0, 0);
            }
        }
    };

    const int NT = K / 64;

    // prologue: DEPTH tiles in flight
#pragma unroll
    for (int d = 0; d < DEPTH; ++d) stage(d, d);

    for (int kt = 0; kt < NT; ++kt) {
        // wait until tile kt's loads complete; keep later tiles in flight
        if constexpr (DEPTH == 2 && CPW == 6) {
            if (kt < NT - 1) asm volatile("s_waitcnt vmcnt(6)" ::: "memory");
            else             asm volatile("s_waitcnt vmcnt(0)" ::: "memory");
        } else if constexpr (DEPTH == 2 && CPW == 4) {
            if (kt < NT - 1) asm volatile("s_waitcnt vmcnt(4)" ::: "memory");
            else             asm volatile("s_waitcnt vmcnt(0)" ::: "memory");
        } else {
            if (kt < NT - 2)       asm volatile("s_waitcnt vmcnt(8)" ::: "memory");
            else if (kt == NT - 2) asm volatile("s_waitcnt vmcnt(4)" ::: "memory");
            else                   asm volatile("s_waitcnt vmcnt(0)" ::: "memory");
        }
        // single barrier: all waves' tile-kt loads landed; also seals WAR for the
        // buffer staged below (last read by all waves in iter kt-1).
        __builtin_amdgcn_s_barrier();

        const char* lb = (const char*)&lds[(kt % NBUF) * BUFE];

        s16x8 af[2][WM], bfr[2][WN];
#pragma unroll
        for (int ks = 0; ks < 2; ++ks) {
#pragma unroll
            for (int m = 0; m < WM; ++m) {
                int row = wy * (BM / 2) + m * 16 + (lane & 15);
                unsigned byte = (unsigned)(row * 128 + (ks * 32 + (lane >> 4) * 8) * 2);
                byte ^= (unsigned)((row & 7) << 4);
                af[ks][m] = *(const s16x8*)(lb + byte);
            }
#pragma unroll
            for (int n = 0; n < WN; ++n) {
                int row = wx * (BN / WCOLS) + n * 16 + (lane & 15);
                unsigned byte = (unsigned)(BM * 128 + row * 128 + (ks * 32 + (lane >> 4) * 8) * 2);
                byte ^= (unsigned)((row & 7) << 4);
                bfr[ks][n] = *(const s16x8*)(lb + byte);
            }
        }

        // issue tile kt+DEPTH while tile kt computes
        if (kt + DEPTH < NT) stage((kt + DEPTH) % NBUF, kt + DEPTH);

#pragma unroll
        for (int ks = 0; ks < 2; ++ks)
#pragma unroll
            for (int m = 0; m < WM; ++m)
#pragma unroll
                for (int n = 0; n < WN; ++n)
                    acc[m][n] = __builtin_amdgcn_mfma_f32_16x16x32_bf16(
                        af[ks][m], bfr[ks][n], acc[m][n], 0, 0, 0);
    }

    // ---- epilogue ----
    float dtv = 0.f;
    if constexpr (EPI >= 1) dtv = tgrid[step + 1] - tgrid[step];

#pragma unroll
    for (int m = 0; m < WM; ++m) {
        int row0 = brow + wy * (BM / 2) + m * 16 + (lane >> 4) * 4;
#pragma unroll
        for (int n = 0; n < WN; ++n) {
            int col = bcol + wx * (BN / WCOLS) + n * 16 + (lane & 15);
            float bv = bias[col];
#pragma unroll
            for (int j = 0; j < 4; ++j) {
                int row = row0 + j;
                float v = acc[m][n][j] + bv;
                if constexpr (EPI == 0) {
                    actOut[(size_t)row * HID + col] = f2bf(fast_tanh(v));
                } else {
                    size_t idx = (size_t)row * DIM + col;
                    if constexpr (EPI == 1) {
                        float yb = ybase[idx];
                        ynext[idx] = yb + (dtv * (1.0f / 6.0f)) * v;
                        ybf[idx] = f2bf(yb + 0.5f * dtv * v);
                    } else if constexpr (EPI == 2) {
                        float yb = ybase[idx];
                        ynext[idx] += (dtv * (1.0f / 3.0f)) * v;
                        ybf[idx] = f2bf(yb + 0.5f * dtv * v);
                    } else if constexpr (EPI == 3) {
                        float yb = ybase[idx];
                        ynext[idx] += (dtv * (1.0f / 3.0f)) * v;
                        ybf[idx] = f2bf(yb + dtv * v);
                    } else {  // EPI == 4
                        float yn = ynext[idx] + (dtv * (1.0f / 6.0f)) * v;
                        ynext[idx] = yn;
                        ybf[idx] = f2bf(yn);
                    }
                }
            }
        }
    }
}

extern "C" void kernel_launch(void* const* d_in, const int* in_sizes, int n_in,
                              void* d_out, int out_size, void* d_ws, size_t ws_size,
                              hipStream_t stream) {
    (void)in_sizes; (void)n_in; (void)out_size; (void)ws_size;
    const float* x0 = (const float*)d_in[0];
    const float* t  = (const float*)d_in[1];
    const float* W1 = (const float*)d_in[2];
    const float* b1 = (const float*)d_in[3];
    const float* W2 = (const float*)d_in[4];
    const float* b2 = (const float*)d_in[5];
    float* out = (float*)d_out;

    char* ws = (char*)d_ws;
    u16*   ybf   = (u16*)  (ws);               //  4 MB  [4096,512]  bf16
    u16*   act   = (u16*)  (ws + (4u  << 20)); //  8 MB  [4096,1024] bf16
    u16*   W1T   = (u16*)  (ws + (12u << 20)); //  1 MB  [1024,512]  bf16
    u16*   W2T   = (u16*)  (ws + (13u << 20)); //  1 MB  [512,1024]  bf16

    init_state<<<(BATCH * DIM + 255) / 256, 256, 0, stream>>>(x0, out, ybf, BATCH * DIM);
    transpose_convert<<<dim3(HID / 32, DIM / 8), dim3(32, 8), 0, stream>>>(W1, W1T, DIM, HID);
    transpose_convert<<<dim3(DIM / 32, HID / 8), dim3(32, 8), 0, stream>>>(W2, W2T, HID, DIM);

    dim3 blk1(512);                    // 8 waves (2x4 wave grid)
    dim3 blk2(256);                    // 4 waves (2x2 wave grid)
    dim3 g1(BATCH / 128, HID / 128);   // 32 x 8 = 256 blocks (1 per CU, 8 waves)
    dim3 g2(512);                      // 1D, XCD-affinity decoded in-kernel

    for (int s = 0; s < TSTEPS - 1; ++s) {
        const float* yb_s = out + (size_t)s * BATCH * DIM;
        float*       yn_s = out + (size_t)(s + 1) * BATCH * DIM;

        // stage 1: k1 = f(y)
        gemm_bt<128,128,0,2,8><<<g1, blk1, 0, stream>>>(ybf, W1T, b1, BATCH, HID, DIM,
                                                        act, nullptr, nullptr, nullptr, nullptr, 0);
        gemm_bt<64,64,1,3,4><<<g2, blk2, 0, stream>>>(act, W2T, b2, BATCH, DIM, HID,
                                                      nullptr, yb_s, yn_s, ybf, t, s);
        // stage 2: k2 = f(y + dt/2 * k1)
        gemm_bt<128,128,0,2,8><<<g1, blk1, 0, stream>>>(ybf, W1T, b1, BATCH, HID, DIM,
                                                        act, nullptr, nullptr, nullptr, nullptr, 0);
        gemm_bt<64,64,2,3,4><<<g2, blk2, 0, stream>>>(act, W2T, b2, BATCH, DIM, HID,
                                                      nullptr, yb_s, yn_s, ybf, t, s);
        // stage 3: k3 = f(y + dt/2 * k2)
        gemm_bt<128,128,0,2,8><<<g1, blk1, 0, stream>>>(ybf, W1T, b1, BATCH, HID, DIM,
                                                        act, nullptr, nullptr, nullptr, nullptr, 0);
        gemm_bt<64,64,3,3,4><<<g2, blk2, 0, stream>>>(act, W2T, b2, BATCH, DIM, HID,
                                                      nullptr, yb_s, yn_s, ybf, t, s);
        // stage 4: y' = y + dt/6 * (k1 + 2k2 + 2k3 + k4)
        gemm_bt<128,128,0,2,8><<<g1, blk1, 0, stream>>>(ybf, W1T, b1, BATCH, HID, DIM,
                                                        act, nullptr, nullptr, nullptr, nullptr, 0);
        gemm_bt<64,64,4,3,4><<<g2, blk2, 0, stream>>>(act, W2T, b2, BATCH, DIM, HID,
                                                      nullptr, yb_s, yn_s, ybf, t, s);
    }
}